// Round 13
// baseline (873.226 us; speedup 1.0000x reference)
//
#include <hip/hip_runtime.h>

typedef _Float16 f16x8 __attribute__((ext_vector_type(8)));
typedef _Float16 f16x4 __attribute__((ext_vector_type(4)));
typedef float f32x4 __attribute__((ext_vector_type(4)));

#define S_DIM 8192
#define D_DIM 512

__device__ __forceinline__ void gload_lds16(const _Float16* g, _Float16* l) {
  __builtin_amdgcn_global_load_lds(
      (const __attribute__((address_space(1))) unsigned int*)g,
      (__attribute__((address_space(3))) unsigned int*)l, 16, 0, 0);
}

__device__ __forceinline__ float sigf(float x) { return 1.0f / (1.0f + __expf(-x)); }
__device__ __forceinline__ float tanhfast(float x) {
  return 1.0f - 2.0f / (__expf(2.0f * x) + 1.0f);
}

// ---------------------------------------------------------------------------
// Tile geometry (BK=64, XOR-swizzled LDS), round-4 proven.
// Round-13: SOFTMAX KERNEL ELIMINATED.  Normalization commutes with the
// readout GEMM: r = (exp(S - m*) @ g) / rowsum.
//  * scores_rel (round-10 proven): P~ = s - m_tile fp16 into 32KB row slots
//    (16KB live + 16KB dead), tile maxes -> M.
//  * rsplit_exp: reg-stages A with on-the-fly p = exp2((P~ + M[nbk]-m*)*l2e)
//    (<= 1), accumulates fp32 row-sums -> Sg[row][kc]; unnormalized fp16
//    partials -> dead row halves.  B stays gload_lds.
//  * reduce_r: sums partials + Sg, multiplies by 1/total.
// ---------------------------------------------------------------------------

// C[m][n] = sum_k A[m][k] * B[n][k];  A:[M x K] lda, B:[N x K] ldb, C fp16 ldc.
// grid = (N/BN, M/BM), 256 threads.
template <int BM, int BN>
__global__ __launch_bounds__(256) void gemm_bt(const _Float16* __restrict__ A, int lda,
                                               const _Float16* __restrict__ B, int ldb,
                                               _Float16* __restrict__ C, int ldc, int K) {
  constexpr int BK = 64;
  constexpr int FM = BM / 32, FN = BN / 32;
  __shared__ _Float16 As[BM * BK];
  __shared__ _Float16 Bs[BN * BK];
  const int tid = threadIdx.x;
  const int lane = tid & 63;
  const int wv = tid >> 6;
  const int bm = blockIdx.y * BM;
  const int bn = blockIdx.x * BN;
  const int wm = (wv >> 1) * (BM / 2);
  const int wn = (wv & 1) * (BN / 2);
  const int fr = lane & 15;
  const int hi4 = lane >> 4;
  const int rx7 = fr & 7;
  const int srow = lane >> 3;
  const int schk = (lane & 7) ^ srow;

  f32x4 acc[FM][FN] = {};

  for (int kt = 0; kt < K; kt += BK) {
    __syncthreads();
#pragma unroll
    for (int p = 0; p < BM / 32; ++p) {
      const int m = wv + 4 * p;
      gload_lds16(A + (size_t)(bm + 8 * m + srow) * lda + kt + schk * 8, As + 512 * m);
    }
#pragma unroll
    for (int p = 0; p < BN / 32; ++p) {
      const int m = wv + 4 * p;
      gload_lds16(B + (size_t)(bn + 8 * m + srow) * ldb + kt + schk * 8, Bs + 512 * m);
    }
    __syncthreads();

#pragma unroll
    for (int h = 0; h < 2; ++h) {
      const int co = (((h << 2) | hi4) ^ rx7) << 3;
      f16x8 af[FM], bf[FN];
#pragma unroll
      for (int i = 0; i < FM; ++i)
        af[i] = *(const f16x8*)&As[(wm + i * 16 + fr) * 64 + co];
#pragma unroll
      for (int j = 0; j < FN; ++j)
        bf[j] = *(const f16x8*)&Bs[(wn + j * 16 + fr) * 64 + co];
#pragma unroll
      for (int i = 0; i < FM; ++i)
#pragma unroll
        for (int j = 0; j < FN; ++j)
          acc[i][j] = __builtin_amdgcn_mfma_f32_16x16x32_f16(af[i], bf[j], acc[i][j], 0, 0, 0);
    }
  }

  const int cc = lane & 15;
  const int cr = (lane >> 4) * 4;
#pragma unroll
  for (int i = 0; i < FM; ++i)
#pragma unroll
    for (int j = 0; j < FN; ++j) {
      size_t base = (size_t)(bm + wm + i * 16 + cr) * ldc + (bn + wn + j * 16 + cc);
#pragma unroll
      for (int r = 0; r < 4; ++r) C[base + (size_t)r * ldc] = (_Float16)acc[i][j][r];
    }
}

// Fused exp + split-K readout.  A = P~ fp16 (lda 16384 halves), transformed
// on the fly: p = exp2((P~ + M[nbk] - m*) * log2e) <= 1.  Unnormalized fp16
// partials -> dead upper halves of P rows; fp32 row-sums -> Sg[row][8]
// (written by nb==0 blocks).  BM=128, BN=128, kc chunk=1024. grid (16,4,8).
__global__ __launch_bounds__(256) void gemm_rsplit_exp(const _Float16* __restrict__ P,
                                                       const _Float16* __restrict__ B,
                                                       const float* __restrict__ M,
                                                       _Float16* __restrict__ Pp,
                                                       float* __restrict__ Sg) {
  __shared__ _Float16 As[128 * 64];
  __shared__ _Float16 Bs[128 * 64];
  __shared__ float Ms[128][8];
  __shared__ float msh[128];
  const int tid = threadIdx.x;
  const int lane = tid & 63;
  const int wv = tid >> 6;
  const int bm = blockIdx.x * 128;
  const int bn = blockIdx.y * 128;
  const int kc = blockIdx.z;
  const int k0 = kc * 1024;
  const int wm = (wv >> 1) * 64;
  const int wn = (wv & 1) * 64;
  const int fr = lane & 15;
  const int hi4 = lane >> 4;
  const int rx7 = fr & 7;
  const int srow = lane >> 3;          // row-in-region 0..7
  const int achk = lane & 7;           // natural A chunk
  const int schk = achk ^ srow;        // pre-swizzled chunk for B gload
  constexpr float L2E = 1.44269504f;

  // prologue: m*[row] = max over all 64 tile maxes; Ms = this chunk's 8
  if (tid < 128) {
    const float* Mr = M + (size_t)(bm + tid) * 64;
    float mm = -3.0e38f;
#pragma unroll
    for (int q = 0; q < 16; ++q) {
      f32x4 v = ((const f32x4*)Mr)[q];
      mm = fmaxf(mm, fmaxf(fmaxf(v[0], v[1]), fmaxf(v[2], v[3])));
    }
    msh[tid] = mm;
#pragma unroll
    for (int j = 0; j < 8; ++j) Ms[tid][j] = Mr[kc * 8 + j];
  }

  f32x4 acc[4][4] = {};
  float psum[4] = {0.f, 0.f, 0.f, 0.f};
  f16x8 areg[4];

  auto load_a = [&](int kt) {
#pragma unroll
    for (int p = 0; p < 4; ++p) {
      const int m = wv + 4 * p;
      areg[p] = *(const f16x8*)(P + (size_t)(bm + 8 * m + srow) * 16384 + kt + achk * 8);
    }
  };

  __syncthreads();  // Ms/msh visible
  load_a(k0);

  for (int kt = k0; kt < k0 + 1024; kt += 64) {
    __syncthreads();  // prev tile's LDS reads done before overwrite
    const int nbk = (kt - k0) >> 7;
    // transform + swizzled ds_write of A(t); accumulate row-sums
#pragma unroll
    for (int p = 0; p < 4; ++p) {
      const int m = wv + 4 * p;
      const int row = 8 * m + srow;
      const float off = (Ms[row][nbk] - msh[row]) * L2E;
      f16x8 o;
      float ps = 0.f;
#pragma unroll
      for (int e = 0; e < 8; ++e) {
        float x = exp2f(fmaf((float)areg[p][e], L2E, off));
        ps += x;
        o[e] = (_Float16)x;
      }
      psum[p] += ps;
      *(f16x8*)&As[512 * m + srow * 64 + (achk ^ srow) * 8] = o;
    }
    // B staging (gload_lds, pre-swizzled source)
#pragma unroll
    for (int p = 0; p < 4; ++p) {
      const int m = wv + 4 * p;
      gload_lds16(B + (size_t)(bn + 8 * m + srow) * 8192 + kt + schk * 8, Bs + 512 * m);
    }
    __syncthreads();
    if (kt + 64 < k0 + 1024) load_a(kt + 64);  // flies under MFMA

#pragma unroll
    for (int h = 0; h < 2; ++h) {
      const int co = (((h << 2) | hi4) ^ rx7) << 3;
      f16x8 af[4], bf[4];
#pragma unroll
      for (int i = 0; i < 4; ++i) {
        af[i] = *(const f16x8*)&As[(wm + i * 16 + fr) * 64 + co];
        bf[i] = *(const f16x8*)&Bs[(wn + i * 16 + fr) * 64 + co];
      }
#pragma unroll
      for (int i = 0; i < 4; ++i)
#pragma unroll
        for (int j = 0; j < 4; ++j)
          acc[i][j] = __builtin_amdgcn_mfma_f32_16x16x32_f16(af[i], bf[j], acc[i][j], 0, 0, 0);
    }
  }

  // row-sums: reduce over the 8 lanes sharing a row; one writer per row
  if (blockIdx.y == 0) {
#pragma unroll
    for (int p = 0; p < 4; ++p) {
      float s = psum[p];
      s += __shfl_xor(s, 1);
      s += __shfl_xor(s, 2);
      s += __shfl_xor(s, 4);
      if ((lane & 7) == 0)
        Sg[(size_t)(bm + 8 * (wv + 4 * p) + srow) * 8 + kc] = s;
    }
  }

  const int cc = lane & 15;
  const int cr = (lane >> 4) * 4;
#pragma unroll
  for (int i = 0; i < 4; ++i)
#pragma unroll
    for (int j = 0; j < 4; ++j) {
      size_t base = (size_t)(bm + wm + i * 16 + cr) * 16384 + 8192 + (size_t)kc * 512 +
                    (bn + wn + j * 16 + cc);
#pragma unroll
      for (int r = 0; r < 4; ++r) Pp[base + (size_t)r * 16384] = (_Float16)acc[i][j][r];
    }
}

// r[m][n] = (sum_kc partial[kc][m][n]) / (sum_kc Sg[m][kc]); fp16 into rbuf.
__global__ __launch_bounds__(256) void reduce_r(const _Float16* __restrict__ Pp,
                                                const float* __restrict__ Sg,
                                                _Float16* __restrict__ rout) {
  int idx = blockIdx.x * 256 + threadIdx.x;  // 0 .. 2048*128-1
  int m = idx >> 7;
  int n4 = (idx & 127) * 4;
  f32x4 s0 = ((const f32x4*)(Sg + (size_t)m * 8))[0];
  f32x4 s1 = ((const f32x4*)(Sg + (size_t)m * 8))[1];
  float inv = 1.0f / ((s0[0] + s0[1] + s0[2] + s0[3]) + (s1[0] + s1[1] + s1[2] + s1[3]));
  const _Float16* base = Pp + (size_t)m * 16384 + 8192 + n4;
  f32x4 s = {0.f, 0.f, 0.f, 0.f};
#pragma unroll
  for (int kc = 0; kc < 8; ++kc) {
    f16x4 v = *(const f16x4*)(base + kc * 512);
#pragma unroll
    for (int e = 0; e < 4; ++e) s[e] += (float)v[e];
  }
  f16x4 h = {(_Float16)(s[0] * inv), (_Float16)(s[1] * inv), (_Float16)(s[2] * inv),
             (_Float16)(s[3] * inv)};
  *(f16x4*)&rout[(size_t)m * 512 + n4] = h;
}

// Split-fp16 scores GEMM (2-term), tile-relative FP16 output (round-10 proven,
// ldc 16384): P~[m][n] = s - m_tile(row), M[m][nb] = m_tile.  grid (64,16).
__global__ __launch_bounds__(256) void gemm_scores_rel(const _Float16* __restrict__ Ah,
                                                       int ldah,
                                                       const _Float16* __restrict__ Al,
                                                       const _Float16* __restrict__ Bh,
                                                       _Float16* __restrict__ P,
                                                       float* __restrict__ M) {
  constexpr int BK = 64;
  __shared__ _Float16 AsH[128 * BK];
  __shared__ _Float16 AsL[128 * BK];
  __shared__ _Float16 BsH[128 * BK];
  __shared__ float rm[2][128];
  const int tid = threadIdx.x;
  const int lane = tid & 63;
  const int wv = tid >> 6;
  const int bm = blockIdx.y * 128;
  const int bn = blockIdx.x * 128;
  const int wm = (wv >> 1) * 64;
  const int wn = (wv & 1) * 64;
  const int fr = lane & 15;
  const int hi4 = lane >> 4;
  const int rx7 = fr & 7;
  const int srow = lane >> 3;
  const int schk = (lane & 7) ^ srow;

  f32x4 acc[4][4] = {};

  for (int kt = 0; kt < 512; kt += BK) {
    __syncthreads();
#pragma unroll
    for (int p = 0; p < 4; ++p) {
      const int m = wv + 4 * p;
      const int row = 8 * m + srow;
      gload_lds16(Ah + (size_t)(bm + row) * ldah + kt + schk * 8, AsH + 512 * m);
      gload_lds16(Al + (size_t)(bm + row) * 512 + kt + schk * 8, AsL + 512 * m);
      gload_lds16(Bh + (size_t)(bn + row) * 512 + kt + schk * 8, BsH + 512 * m);
    }
    __syncthreads();

#pragma unroll
    for (int h = 0; h < 2; ++h) {
      const int co = (((h << 2) | hi4) ^ rx7) << 3;
      f16x8 fah[4], fal[4], fbh[4];
#pragma unroll
      for (int i = 0; i < 4; ++i) {
        fah[i] = *(const f16x8*)&AsH[(wm + i * 16 + fr) * 64 + co];
        fal[i] = *(const f16x8*)&AsL[(wm + i * 16 + fr) * 64 + co];
        fbh[i] = *(const f16x8*)&BsH[(wn + i * 16 + fr) * 64 + co];
      }
#pragma unroll
      for (int i = 0; i < 4; ++i)
#pragma unroll
        for (int j = 0; j < 4; ++j) {
          acc[i][j] = __builtin_amdgcn_mfma_f32_16x16x32_f16(fah[i], fbh[j], acc[i][j], 0, 0, 0);
          acc[i][j] = __builtin_amdgcn_mfma_f32_16x16x32_f16(fal[i], fbh[j], acc[i][j], 0, 0, 0);
        }
    }
  }

  // Epilogue: per-row tile max -> M; store fp16 (s - m_tile) at stride 16384.
  const int cc = lane & 15;
  const int cr = (lane >> 4) * 4;
  float rmax[4][4];
#pragma unroll
  for (int i = 0; i < 4; ++i)
#pragma unroll
    for (int r = 0; r < 4; ++r) {
      float m0 = fmaxf(fmaxf(acc[i][0][r], acc[i][1][r]),
                       fmaxf(acc[i][2][r], acc[i][3][r]));
#pragma unroll
      for (int o = 1; o < 16; o <<= 1) m0 = fmaxf(m0, __shfl_xor(m0, o));
      rmax[i][r] = m0;
    }
  if (cc == 0) {
#pragma unroll
    for (int i = 0; i < 4; ++i)
#pragma unroll
      for (int r = 0; r < 4; ++r) rm[wv & 1][wm + i * 16 + cr + r] = rmax[i][r];
  }
  __syncthreads();
#pragma unroll
  for (int i = 0; i < 4; ++i)
#pragma unroll
    for (int r = 0; r < 4; ++r) {
      const int row = wm + i * 16 + cr + r;
      const float mt = fmaxf(rm[0][row], rm[1][row]);
      if (cc == 0 && (wv & 1) == 0)
        M[(size_t)(bm + row) * 64 + blockIdx.x] = mt;
#pragma unroll
      for (int j = 0; j < 4; ++j)
        P[(size_t)(bm + row) * 16384 + bn + wn + j * 16 + cc] =
            (_Float16)(acc[i][j][r] - mt);
    }
}

// Fused gates GEMM + LSTM cell (round-9 proven).  grid (16 n, 32 m).
__global__ __launch_bounds__(256) void gemm_gates(const _Float16* __restrict__ Ah,
                                                  const _Float16* __restrict__ Ar,
                                                  const _Float16* __restrict__ B,
                                                  const _Float16* __restrict__ gbase,
                                                  const float* __restrict__ bsum,
                                                  const float* __restrict__ f_x,
                                                  float* __restrict__ c,
                                                  _Float16* __restrict__ hnext,
                                                  _Float16* __restrict__ h_lo,
                                                  float* __restrict__ hout) {
  __shared__ _Float16 As[128 * 64];
  __shared__ _Float16 Bs[128 * 64];
  const int tid = threadIdx.x;
  const int lane = tid & 63;
  const int wv = tid >> 6;
  const int n0 = blockIdx.x * 32;
  const int bm = blockIdx.y * 128;
  const int fr = lane & 15;
  const int hi4 = lane >> 4;
  const int rx7 = fr & 7;
  const int srow = lane >> 3;
  const int schk = (lane & 7) ^ srow;

  f32x4 acc[2][8] = {};

  for (int t = 0; t < 16; ++t) {
    const int kt = t * 64;
    __syncthreads();
#pragma unroll
    for (int p = 0; p < 4; ++p) {
      const int m = wv + 4 * p;
      const int arow = bm + 8 * m + srow;
      const _Float16* asrc = (t < 8)
                                 ? Ah + (size_t)arow * 512 + kt + schk * 8
                                 : Ar + (size_t)arow * 512 + (kt - 512) + schk * 8;
      gload_lds16(asrc, As + 512 * m);
      const int brow = 8 * m + srow;  // 0..127
      const int wrow = ((brow >> 5) << 9) + n0 + (brow & 31);
      gload_lds16(B + (size_t)wrow * 1024 + kt + schk * 8, Bs + 512 * m);
    }
    __syncthreads();

#pragma unroll
    for (int h = 0; h < 2; ++h) {
      const int co = (((h << 2) | hi4) ^ rx7) << 3;
      f16x8 af[2], bf[8];
#pragma unroll
      for (int i = 0; i < 2; ++i)
        af[i] = *(const f16x8*)&As[(wv * 32 + i * 16 + fr) * 64 + co];
#pragma unroll
      for (int j = 0; j < 8; ++j)
        bf[j] = *(const f16x8*)&Bs[(j * 16 + fr) * 64 + co];
#pragma unroll
      for (int i = 0; i < 2; ++i)
#pragma unroll
        for (int j = 0; j < 8; ++j)
          acc[i][j] = __builtin_amdgcn_mfma_f32_16x16x32_f16(af[i], bf[j], acc[i][j], 0, 0, 0);
    }
  }

  const int cc = lane & 15;
  const int cr = (lane >> 4) * 4;
#pragma unroll
  for (int jj = 0; jj < 2; ++jj) {
    const int colq = n0 + jj * 16 + cc;  // 0..511
    const float bI = bsum[colq];
    const float bF = bsum[colq + 512];
    const float bG = bsum[colq + 1024];
    const float bO = bsum[colq + 1536];
#pragma unroll
    for (int i = 0; i < 2; ++i)
#pragma unroll
      for (int r = 0; r < 4; ++r) {
        const int row = bm + wv * 32 + i * 16 + cr + r;
        const size_t g0 = (size_t)row * 2048 + colq;
        const float gi = acc[i][jj][r] + (float)gbase[g0] + bI;
        const float gf = acc[i][2 + jj][r] + (float)gbase[g0 + 512] + bF;
        const float gg = acc[i][4 + jj][r] + (float)gbase[g0 + 1024] + bG;
        const float go = acc[i][6 + jj][r] + (float)gbase[g0 + 1536] + bO;
        const size_t o = (size_t)row * 512 + colq;
        const float ci = sigf(gf) * c[o] + sigf(gi) * tanhfast(gg);
        const float hi = sigf(go) * tanhfast(ci) + f_x[o];
        c[o] = ci;
        hout[o] = hi;
        const _Float16 h16 = (_Float16)hi;
        hnext[o] = h16;
        h_lo[o] = (_Float16)(hi - (float)h16);
      }
  }
}

// transpose g [8192x512] f32 -> gT [512x8192] f16; also g_hi f16
__global__ __launch_bounds__(256) void prep_g(const float* __restrict__ g,
                                              _Float16* __restrict__ gT,
                                              _Float16* __restrict__ g_h) {
  __shared__ _Float16 tile[64][72];
  const int s0 = blockIdx.x * 64;
  const int d0 = blockIdx.y * 64;
  const int t = threadIdx.x;
  const int r = t >> 2;
  const int cq = (t & 3) * 16;
  alignas(16) _Float16 buf[16];
#pragma unroll
  for (int q = 0; q < 4; ++q) {
    f32x4 v = *(const f32x4*)&g[(size_t)(s0 + r) * D_DIM + d0 + cq + q * 4];
#pragma unroll
    for (int e = 0; e < 4; ++e) buf[q * 4 + e] = (_Float16)v[e];
  }
#pragma unroll
  for (int k = 0; k < 16; ++k) tile[r][cq + k] = buf[k];
  *(f16x8*)&g_h[(size_t)(s0 + r) * D_DIM + d0 + cq] = *(const f16x8*)&buf[0];
  *(f16x8*)&g_h[(size_t)(s0 + r) * D_DIM + d0 + cq + 8] = *(const f16x8*)&buf[8];
  __syncthreads();
  alignas(16) _Float16 ob[16];
#pragma unroll
  for (int k = 0; k < 16; ++k) ob[k] = tile[cq + k][r];
  *(f16x8*)&gT[(size_t)(d0 + r) * S_DIM + s0 + cq] = *(const f16x8*)&ob[0];
  *(f16x8*)&gT[(size_t)(d0 + r) * S_DIM + s0 + cq + 8] = *(const f16x8*)&ob[8];
}

// convert W_ih, W_hh to f16; init hbufA=f16(f_x), h_lo=residual; zero c;
// bsum = b_ih + b_hh.
__global__ __launch_bounds__(256) void prep_misc(const float* __restrict__ W_ih,
                                                 const float* __restrict__ W_hh,
                                                 const float* __restrict__ f_x,
                                                 const float* __restrict__ b_ih,
                                                 const float* __restrict__ b_hh,
                                                 _Float16* __restrict__ wih_h,
                                                 _Float16* __restrict__ whh_h,
                                                 _Float16* __restrict__ hbufA,
                                                 _Float16* __restrict__ h_lo,
                                                 float* __restrict__ c,
                                                 float* __restrict__ bsum) {
  const int NW1 = 2048 * 512 / 4;
  const int NW2 = 2048 * 1024 / 4;
  const int NFX = 4096 * 512 / 4;
  int idx = blockIdx.x * 256 + threadIdx.x;
  if (idx < NW1) {
    f32x4 v = ((const f32x4*)W_ih)[idx];
    f16x4 h = {(_Float16)v[0], (_Float16)v[1], (_Float16)v[2], (_Float16)v[3]};
    ((f16x4*)wih_h)[idx] = h;
  } else if (idx < NW1 + NW2) {
    int k = idx - NW1;
    f32x4 v = ((const f32x4*)W_hh)[k];
    f16x4 h = {(_Float16)v[0], (_Float16)v[1], (_Float16)v[2], (_Float16)v[3]};
    ((f16x4*)whh_h)[k] = h;
  } else if (idx < NW1 + NW2 + NFX) {
    int k = idx - NW1 - NW2;
    f32x4 v = ((const f32x4*)f_x)[k];
    f16x4 h, lo;
#pragma unroll
    for (int e = 0; e < 4; ++e) {
      h[e] = (_Float16)v[e];
      lo[e] = (_Float16)(v[e] - (float)h[e]);
    }
    ((f16x4*)hbufA)[k] = h;
    ((f16x4*)h_lo)[k] = lo;
    f32x4 z = {0.f, 0.f, 0.f, 0.f};
    ((f32x4*)c)[k] = z;
  } else if (idx < NW1 + NW2 + NFX + 512) {
    int k = idx - NW1 - NW2 - NFX;
    f32x4 bi = ((const f32x4*)b_ih)[k];
    f32x4 bh = ((const f32x4*)b_hh)[k];
    ((f32x4*)bsum)[k] = bi + bh;
  }
}

extern "C" void kernel_launch(void* const* d_in, const int* in_sizes, int n_in,
                              void* d_out, int out_size, void* d_ws, size_t ws_size,
                              hipStream_t stream) {
  const float* f_x = (const float*)d_in[0];   // [4096,512]
  const float* g_S = (const float*)d_in[1];   // [8192,512]
  const float* W_ih = (const float*)d_in[2];  // [2048,512]
  const float* W_hh = (const float*)d_in[3];  // [2048,1024]
  const float* b_ih = (const float*)d_in[4];  // [2048]
  const float* b_hh = (const float*)d_in[5];  // [2048]
  float* hout = (float*)d_out;                // [4096,512]

  char* w = (char*)d_ws;
  _Float16* P16 = (_Float16*)w;                        // 2048 rows x 32KB slots = 67108864
  _Float16* gbase = (_Float16*)(w + 67108864);         // 4096*2048*2 = 16777216
  _Float16* hbufA = (_Float16*)(w + 83886080);         // 4096*512*2  = 4194304
  _Float16* hbufB = (_Float16*)(w + 88080384);         // 4096*512*2  = 4194304
  _Float16* g_h = (_Float16*)(w + 92274688);           // 8192*512*2  = 8388608
  _Float16* rbuf = (_Float16*)(w + 100663296);         // 4096*512*2  = 4194304
  float* bsum = (float*)(w + 104857600);               // 2048*4      = 8192
  float* Sg = (float*)(w + 104865792);                 // 2048*8*4    = 65536
  float* Mbuf = (float*)(w + 104931328);               // 2048*64*4   = 524288
  _Float16* gT = (_Float16*)(w + 109051904);           // 512*8192*2  = 8388608
  _Float16* wih_h = (_Float16*)(w + 117440512);        // 2048*512*2  = 2097152
  _Float16* whh_h = (_Float16*)(w + 119537664);        // 2048*1024*2 = 4194304
  float* c = (float*)(w + 123731968);                  // 4096*512*4  = 8388608
  _Float16* h_lo = (_Float16*)(w + 132120576);         // 4096*512*2  = 4194304
  // total 136314880 bytes (unchanged)

  prep_g<<<dim3(S_DIM / 64, D_DIM / 64), 256, 0, stream>>>(g_S, gT, g_h);
  prep_misc<<<5122, 256, 0, stream>>>(W_ih, W_hh, f_x, b_ih, b_hh, wih_h, whh_h,
                                      hbufA, h_lo, c, bsum);

  // gbase = f_x @ W_ih^T  (A = hbufA = f16(f_x), lda 512)
  gemm_bt<128, 128><<<dim3(2048 / 128, 4096 / 128), 256, 0, stream>>>(
      hbufA, 512, wih_h, 512, gbase, 2048, 512);

  for (int it = 0; it < 4; ++it) {
    _Float16* hcur = (it & 1) ? hbufB : hbufA;
    _Float16* hnxt = (it & 1) ? hbufA : hbufB;
    for (int hb = 0; hb < 2; ++hb) {
      const _Float16* hhi = hcur + (size_t)hb * 2048 * 512;
      const _Float16* hlo = h_lo + (size_t)hb * 2048 * 512;
      // P~ = h @ g^T - m_tile (fp16, stride 16384) + tile maxes M
      gemm_scores_rel<<<dim3(64, 16), 256, 0, stream>>>(hhi, 512, hlo, g_h, P16, Mbuf);
      // r-partials = exp(P~ + M - m*) @ g (split-K, fp16) + row-sums Sg
      gemm_rsplit_exp<<<dim3(16, 4, 8), 256, 0, stream>>>(P16, gT, Mbuf, P16, Sg);
      // r = (sum partials) / (sum Sg) -> rbuf
      reduce_r<<<1024, 256, 0, stream>>>(P16, Sg, rbuf + (size_t)hb * 2048 * 512);
    }
    // gates = [h|r] @ W_hh^T + gbase + bsum -> LSTM cell fused in epilogue
    gemm_gates<<<dim3(16, 32), 256, 0, stream>>>(hcur, rbuf, whh_h, gbase, bsum,
                                                 f_x, c, hnxt, h_lo, hout);
  }
  (void)in_sizes; (void)n_in; (void)out_size; (void)ws_size;
}

// Round 14
// 851.367 us; speedup vs baseline: 1.0257x; 1.0257x over previous
//
#include <hip/hip_runtime.h>

typedef _Float16 f16x8 __attribute__((ext_vector_type(8)));
typedef _Float16 f16x4 __attribute__((ext_vector_type(4)));
typedef float f32x4 __attribute__((ext_vector_type(4)));

#define S_DIM 8192
#define D_DIM 512

__device__ __forceinline__ void gload_lds16(const _Float16* g, _Float16* l) {
  __builtin_amdgcn_global_load_lds(
      (const __attribute__((address_space(1))) unsigned int*)g,
      (__attribute__((address_space(3))) unsigned int*)l, 16, 0, 0);
}

__device__ __forceinline__ float sigf(float x) { return 1.0f / (1.0f + __expf(-x)); }
__device__ __forceinline__ float tanhfast(float x) {
  return 1.0f - 2.0f / (__expf(2.0f * x) + 1.0f);
}

// ---------------------------------------------------------------------------
// Tile geometry (BK=64, XOR-swizzled LDS), round-4 proven.
// Round-14: REVERT to the round-12 configuration (best measured: 852us).
// Round-13's softmax-into-rsplit fusion measured NEGATIVE (+21us): the
// 32 exp2/thread/K-step made rsplit VALU-bound (VALUBusy 40.6, MfmaUtil
// 13.5) -- elementwise work fused into a GEMM that isn't VALU-idle loses.
// Config: plain fp32 scores + in-place softmax + fp16 split-K partials in
// dead P-row halves + 128x128 rsplit + fused gates+LSTM.
// ---------------------------------------------------------------------------

// C[m][n] = sum_k A[m][k] * B[n][k];  A:[M x K] lda, B:[N x K] ldb, C fp16 ldc.
// grid = (N/BN, M/BM), 256 threads.
template <int BM, int BN>
__global__ __launch_bounds__(256) void gemm_bt(const _Float16* __restrict__ A, int lda,
                                               const _Float16* __restrict__ B, int ldb,
                                               _Float16* __restrict__ C, int ldc, int K) {
  constexpr int BK = 64;
  constexpr int FM = BM / 32, FN = BN / 32;
  __shared__ _Float16 As[BM * BK];
  __shared__ _Float16 Bs[BN * BK];
  const int tid = threadIdx.x;
  const int lane = tid & 63;
  const int wv = tid >> 6;
  const int bm = blockIdx.y * BM;
  const int bn = blockIdx.x * BN;
  const int wm = (wv >> 1) * (BM / 2);
  const int wn = (wv & 1) * (BN / 2);
  const int fr = lane & 15;
  const int hi4 = lane >> 4;
  const int rx7 = fr & 7;
  const int srow = lane >> 3;
  const int schk = (lane & 7) ^ srow;

  f32x4 acc[FM][FN] = {};

  for (int kt = 0; kt < K; kt += BK) {
    __syncthreads();
#pragma unroll
    for (int p = 0; p < BM / 32; ++p) {
      const int m = wv + 4 * p;
      gload_lds16(A + (size_t)(bm + 8 * m + srow) * lda + kt + schk * 8, As + 512 * m);
    }
#pragma unroll
    for (int p = 0; p < BN / 32; ++p) {
      const int m = wv + 4 * p;
      gload_lds16(B + (size_t)(bn + 8 * m + srow) * ldb + kt + schk * 8, Bs + 512 * m);
    }
    __syncthreads();

#pragma unroll
    for (int h = 0; h < 2; ++h) {
      const int co = (((h << 2) | hi4) ^ rx7) << 3;
      f16x8 af[FM], bf[FN];
#pragma unroll
      for (int i = 0; i < FM; ++i)
        af[i] = *(const f16x8*)&As[(wm + i * 16 + fr) * 64 + co];
#pragma unroll
      for (int j = 0; j < FN; ++j)
        bf[j] = *(const f16x8*)&Bs[(wn + j * 16 + fr) * 64 + co];
#pragma unroll
      for (int i = 0; i < FM; ++i)
#pragma unroll
        for (int j = 0; j < FN; ++j)
          acc[i][j] = __builtin_amdgcn_mfma_f32_16x16x32_f16(af[i], bf[j], acc[i][j], 0, 0, 0);
    }
  }

  const int cc = lane & 15;
  const int cr = (lane >> 4) * 4;
#pragma unroll
  for (int i = 0; i < FM; ++i)
#pragma unroll
    for (int j = 0; j < FN; ++j) {
      size_t base = (size_t)(bm + wm + i * 16 + cr) * ldc + (bn + wn + j * 16 + cc);
#pragma unroll
      for (int r = 0; r < 4; ++r) C[base + (size_t)r * ldc] = (_Float16)acc[i][j][r];
    }
}

// Split-K readout partials.  A = P fp16 probs (lda 16384, first half of each
// P32 row slot), B = gT (ldb 8192).  Partials FP16 into the dead second half:
// fp16 index m*16384 + 8192 + kc*512 + n.  BM=128, BN=128. grid (16,4,8):
// same-A-panel blocks (same mb,kc; 4 nb) have linear stride 16 == 0 mod 8.
__global__ __launch_bounds__(256) void gemm_rsplit(const _Float16* __restrict__ A,
                                                   const _Float16* __restrict__ B,
                                                   _Float16* __restrict__ Pp) {
  constexpr int BK = 64;
  __shared__ _Float16 As[128 * BK];
  __shared__ _Float16 Bs[128 * BK];
  const int tid = threadIdx.x;
  const int lane = tid & 63;
  const int wv = tid >> 6;
  const int bm = blockIdx.x * 128;
  const int bn = blockIdx.y * 128;
  const int kc = blockIdx.z;
  const int k0 = kc * 1024;
  const int wm = (wv >> 1) * 64;
  const int wn = (wv & 1) * 64;
  const int fr = lane & 15;
  const int hi4 = lane >> 4;
  const int rx7 = fr & 7;
  const int srow = lane >> 3;
  const int schk = (lane & 7) ^ srow;

  f32x4 acc[4][4] = {};

  for (int kt = k0; kt < k0 + 1024; kt += BK) {
    __syncthreads();
#pragma unroll
    for (int p = 0; p < 4; ++p) {
      const int m = wv + 4 * p;
      gload_lds16(A + (size_t)(bm + 8 * m + srow) * 16384 + kt + schk * 8, As + 512 * m);
      gload_lds16(B + (size_t)(bn + 8 * m + srow) * 8192 + kt + schk * 8, Bs + 512 * m);
    }
    __syncthreads();

#pragma unroll
    for (int h = 0; h < 2; ++h) {
      const int co = (((h << 2) | hi4) ^ rx7) << 3;
      f16x8 af[4], bf[4];
#pragma unroll
      for (int i = 0; i < 4; ++i) {
        af[i] = *(const f16x8*)&As[(wm + i * 16 + fr) * 64 + co];
        bf[i] = *(const f16x8*)&Bs[(wn + i * 16 + fr) * 64 + co];
      }
#pragma unroll
      for (int i = 0; i < 4; ++i)
#pragma unroll
        for (int j = 0; j < 4; ++j)
          acc[i][j] = __builtin_amdgcn_mfma_f32_16x16x32_f16(af[i], bf[j], acc[i][j], 0, 0, 0);
    }
  }

  const int cc = lane & 15;
  const int cr = (lane >> 4) * 4;
#pragma unroll
  for (int i = 0; i < 4; ++i)
#pragma unroll
    for (int j = 0; j < 4; ++j) {
      size_t base = (size_t)(bm + wm + i * 16 + cr) * 16384 + 8192 + (size_t)kc * 512 +
                    (bn + wn + j * 16 + cc);
#pragma unroll
      for (int r = 0; r < 4; ++r) Pp[base + (size_t)r * 16384] = (_Float16)acc[i][j][r];
    }
}

// r[m][n] = sum_kc fp16 partial[kc][m][n] (fp32 accum); fp16 into rbuf (ld 512).
__global__ __launch_bounds__(256) void reduce_r(const _Float16* __restrict__ Pp,
                                                _Float16* __restrict__ rout) {
  int idx = blockIdx.x * 256 + threadIdx.x;  // 0 .. 2048*128-1
  int m = idx >> 7;
  int n4 = (idx & 127) * 4;
  const _Float16* base = Pp + (size_t)m * 16384 + 8192 + n4;
  f32x4 s = {0.f, 0.f, 0.f, 0.f};
#pragma unroll
  for (int kc = 0; kc < 8; ++kc) {
    f16x4 v = *(const f16x4*)(base + kc * 512);
#pragma unroll
    for (int e = 0; e < 4; ++e) s[e] += (float)v[e];
  }
  f16x4 h = {(_Float16)s[0], (_Float16)s[1], (_Float16)s[2], (_Float16)s[3]};
  *(f16x4*)&rout[(size_t)m * 512 + n4] = h;
}

// Split-fp16 scores GEMM (2-term, round-6 proven): C(f32) = (Ah+Al) @ Bh^T.
// BM=BN=128, K=512. grid (64, 16), default mapping (no swizzle).
__global__ __launch_bounds__(256) void gemm_scores(const _Float16* __restrict__ Ah, int ldah,
                                                   const _Float16* __restrict__ Al,
                                                   const _Float16* __restrict__ Bh,
                                                   float* __restrict__ C) {
  constexpr int BK = 64;
  __shared__ _Float16 AsH[128 * BK];
  __shared__ _Float16 AsL[128 * BK];
  __shared__ _Float16 BsH[128 * BK];
  const int tid = threadIdx.x;
  const int lane = tid & 63;
  const int wv = tid >> 6;
  const int bm = blockIdx.y * 128;
  const int bn = blockIdx.x * 128;
  const int wm = (wv >> 1) * 64;
  const int wn = (wv & 1) * 64;
  const int fr = lane & 15;
  const int hi4 = lane >> 4;
  const int rx7 = fr & 7;
  const int srow = lane >> 3;
  const int schk = (lane & 7) ^ srow;

  f32x4 acc[4][4] = {};

  for (int kt = 0; kt < 512; kt += BK) {
    __syncthreads();
#pragma unroll
    for (int p = 0; p < 4; ++p) {
      const int m = wv + 4 * p;
      const int row = 8 * m + srow;
      gload_lds16(Ah + (size_t)(bm + row) * ldah + kt + schk * 8, AsH + 512 * m);
      gload_lds16(Al + (size_t)(bm + row) * 512 + kt + schk * 8, AsL + 512 * m);
      gload_lds16(Bh + (size_t)(bn + row) * 512 + kt + schk * 8, BsH + 512 * m);
    }
    __syncthreads();

#pragma unroll
    for (int h = 0; h < 2; ++h) {
      const int co = (((h << 2) | hi4) ^ rx7) << 3;
      f16x8 fah[4], fal[4], fbh[4];
#pragma unroll
      for (int i = 0; i < 4; ++i) {
        fah[i] = *(const f16x8*)&AsH[(wm + i * 16 + fr) * 64 + co];
        fal[i] = *(const f16x8*)&AsL[(wm + i * 16 + fr) * 64 + co];
        fbh[i] = *(const f16x8*)&BsH[(wn + i * 16 + fr) * 64 + co];
      }
#pragma unroll
      for (int i = 0; i < 4; ++i)
#pragma unroll
        for (int j = 0; j < 4; ++j) {
          acc[i][j] = __builtin_amdgcn_mfma_f32_16x16x32_f16(fah[i], fbh[j], acc[i][j], 0, 0, 0);
          acc[i][j] = __builtin_amdgcn_mfma_f32_16x16x32_f16(fal[i], fbh[j], acc[i][j], 0, 0, 0);
        }
    }
  }

  const int cc = lane & 15;
  const int cr = (lane >> 4) * 4;
#pragma unroll
  for (int i = 0; i < 4; ++i)
#pragma unroll
    for (int j = 0; j < 4; ++j) {
      size_t base = (size_t)(bm + wm + i * 16 + cr) * 8192 + (bn + wn + j * 16 + cc);
#pragma unroll
      for (int r = 0; r < 4; ++r) C[base + (size_t)r * 8192] = acc[i][j][r];
    }
}

// Fused gates GEMM + LSTM cell (round-9 proven).  grid (16 n, 32 m).
__global__ __launch_bounds__(256) void gemm_gates(const _Float16* __restrict__ Ah,
                                                  const _Float16* __restrict__ Ar,
                                                  const _Float16* __restrict__ B,
                                                  const _Float16* __restrict__ gbase,
                                                  const float* __restrict__ bsum,
                                                  const float* __restrict__ f_x,
                                                  float* __restrict__ c,
                                                  _Float16* __restrict__ hnext,
                                                  _Float16* __restrict__ h_lo,
                                                  float* __restrict__ hout) {
  __shared__ _Float16 As[128 * 64];
  __shared__ _Float16 Bs[128 * 64];
  const int tid = threadIdx.x;
  const int lane = tid & 63;
  const int wv = tid >> 6;
  const int n0 = blockIdx.x * 32;
  const int bm = blockIdx.y * 128;
  const int fr = lane & 15;
  const int hi4 = lane >> 4;
  const int rx7 = fr & 7;
  const int srow = lane >> 3;
  const int schk = (lane & 7) ^ srow;

  f32x4 acc[2][8] = {};

  for (int t = 0; t < 16; ++t) {
    const int kt = t * 64;
    __syncthreads();
#pragma unroll
    for (int p = 0; p < 4; ++p) {
      const int m = wv + 4 * p;
      const int arow = bm + 8 * m + srow;
      const _Float16* asrc = (t < 8)
                                 ? Ah + (size_t)arow * 512 + kt + schk * 8
                                 : Ar + (size_t)arow * 512 + (kt - 512) + schk * 8;
      gload_lds16(asrc, As + 512 * m);
      const int brow = 8 * m + srow;  // 0..127
      const int wrow = ((brow >> 5) << 9) + n0 + (brow & 31);
      gload_lds16(B + (size_t)wrow * 1024 + kt + schk * 8, Bs + 512 * m);
    }
    __syncthreads();

#pragma unroll
    for (int h = 0; h < 2; ++h) {
      const int co = (((h << 2) | hi4) ^ rx7) << 3;
      f16x8 af[2], bf[8];
#pragma unroll
      for (int i = 0; i < 2; ++i)
        af[i] = *(const f16x8*)&As[(wv * 32 + i * 16 + fr) * 64 + co];
#pragma unroll
      for (int j = 0; j < 8; ++j)
        bf[j] = *(const f16x8*)&Bs[(j * 16 + fr) * 64 + co];
#pragma unroll
      for (int i = 0; i < 2; ++i)
#pragma unroll
        for (int j = 0; j < 8; ++j)
          acc[i][j] = __builtin_amdgcn_mfma_f32_16x16x32_f16(af[i], bf[j], acc[i][j], 0, 0, 0);
    }
  }

  const int cc = lane & 15;
  const int cr = (lane >> 4) * 4;
#pragma unroll
  for (int jj = 0; jj < 2; ++jj) {
    const int colq = n0 + jj * 16 + cc;  // 0..511
    const float bI = bsum[colq];
    const float bF = bsum[colq + 512];
    const float bG = bsum[colq + 1024];
    const float bO = bsum[colq + 1536];
#pragma unroll
    for (int i = 0; i < 2; ++i)
#pragma unroll
      for (int r = 0; r < 4; ++r) {
        const int row = bm + wv * 32 + i * 16 + cr + r;
        const size_t g0 = (size_t)row * 2048 + colq;
        const float gi = acc[i][jj][r] + (float)gbase[g0] + bI;
        const float gf = acc[i][2 + jj][r] + (float)gbase[g0 + 512] + bF;
        const float gg = acc[i][4 + jj][r] + (float)gbase[g0 + 1024] + bG;
        const float go = acc[i][6 + jj][r] + (float)gbase[g0 + 1536] + bO;
        const size_t o = (size_t)row * 512 + colq;
        const float ci = sigf(gf) * c[o] + sigf(gi) * tanhfast(gg);
        const float hi = sigf(go) * tanhfast(ci) + f_x[o];
        c[o] = ci;
        hout[o] = hi;
        const _Float16 h16 = (_Float16)hi;
        hnext[o] = h16;
        h_lo[o] = (_Float16)(hi - (float)h16);
      }
  }
}

// transpose g [8192x512] f32 -> gT [512x8192] f16; also g_hi f16
__global__ __launch_bounds__(256) void prep_g(const float* __restrict__ g,
                                              _Float16* __restrict__ gT,
                                              _Float16* __restrict__ g_h) {
  __shared__ _Float16 tile[64][72];
  const int s0 = blockIdx.x * 64;
  const int d0 = blockIdx.y * 64;
  const int t = threadIdx.x;
  const int r = t >> 2;
  const int cq = (t & 3) * 16;
  alignas(16) _Float16 buf[16];
#pragma unroll
  for (int q = 0; q < 4; ++q) {
    f32x4 v = *(const f32x4*)&g[(size_t)(s0 + r) * D_DIM + d0 + cq + q * 4];
#pragma unroll
    for (int e = 0; e < 4; ++e) buf[q * 4 + e] = (_Float16)v[e];
  }
#pragma unroll
  for (int k = 0; k < 16; ++k) tile[r][cq + k] = buf[k];
  *(f16x8*)&g_h[(size_t)(s0 + r) * D_DIM + d0 + cq] = *(const f16x8*)&buf[0];
  *(f16x8*)&g_h[(size_t)(s0 + r) * D_DIM + d0 + cq + 8] = *(const f16x8*)&buf[8];
  __syncthreads();
  alignas(16) _Float16 ob[16];
#pragma unroll
  for (int k = 0; k < 16; ++k) ob[k] = tile[cq + k][r];
  *(f16x8*)&gT[(size_t)(d0 + r) * S_DIM + s0 + cq] = *(const f16x8*)&ob[0];
  *(f16x8*)&gT[(size_t)(d0 + r) * S_DIM + s0 + cq + 8] = *(const f16x8*)&ob[8];
}

// convert W_ih, W_hh to f16; init hbufA=f16(f_x), h_lo=residual; zero c;
// bsum = b_ih + b_hh.
__global__ __launch_bounds__(256) void prep_misc(const float* __restrict__ W_ih,
                                                 const float* __restrict__ W_hh,
                                                 const float* __restrict__ f_x,
                                                 const float* __restrict__ b_ih,
                                                 const float* __restrict__ b_hh,
                                                 _Float16* __restrict__ wih_h,
                                                 _Float16* __restrict__ whh_h,
                                                 _Float16* __restrict__ hbufA,
                                                 _Float16* __restrict__ h_lo,
                                                 float* __restrict__ c,
                                                 float* __restrict__ bsum) {
  const int NW1 = 2048 * 512 / 4;
  const int NW2 = 2048 * 1024 / 4;
  const int NFX = 4096 * 512 / 4;
  int idx = blockIdx.x * 256 + threadIdx.x;
  if (idx < NW1) {
    f32x4 v = ((const f32x4*)W_ih)[idx];
    f16x4 h = {(_Float16)v[0], (_Float16)v[1], (_Float16)v[2], (_Float16)v[3]};
    ((f16x4*)wih_h)[idx] = h;
  } else if (idx < NW1 + NW2) {
    int k = idx - NW1;
    f32x4 v = ((const f32x4*)W_hh)[k];
    f16x4 h = {(_Float16)v[0], (_Float16)v[1], (_Float16)v[2], (_Float16)v[3]};
    ((f16x4*)whh_h)[k] = h;
  } else if (idx < NW1 + NW2 + NFX) {
    int k = idx - NW1 - NW2;
    f32x4 v = ((const f32x4*)f_x)[k];
    f16x4 h, lo;
#pragma unroll
    for (int e = 0; e < 4; ++e) {
      h[e] = (_Float16)v[e];
      lo[e] = (_Float16)(v[e] - (float)h[e]);
    }
    ((f16x4*)hbufA)[k] = h;
    ((f16x4*)h_lo)[k] = lo;
    f32x4 z = {0.f, 0.f, 0.f, 0.f};
    ((f32x4*)c)[k] = z;
  } else if (idx < NW1 + NW2 + NFX + 512) {
    int k = idx - NW1 - NW2 - NFX;
    f32x4 bi = ((const f32x4*)b_ih)[k];
    f32x4 bh = ((const f32x4*)b_hh)[k];
    ((f32x4*)bsum)[k] = bi + bh;
  }
}

// row softmax: read fp32 scores (8192), write fp16 probs in place (first half
// of the row's 32KB slot). One block per row; race-free in-place convert.
__global__ __launch_bounds__(256) void softmax_inplace(float* __restrict__ P) {
  float* p = P + (size_t)blockIdx.x * S_DIM;
  const int tid = threadIdx.x, lane = tid & 63, wave = tid >> 6;
  __shared__ float red[8];
  float x[32];
#pragma unroll
  for (int i = 0; i < 8; ++i) {
    f32x4 v = *(const f32x4*)&p[i * 1024 + tid * 4];
#pragma unroll
    for (int j = 0; j < 4; ++j) x[i * 4 + j] = v[j];
  }
  float m = -3.0e38f;
#pragma unroll
  for (int k = 0; k < 32; ++k) m = fmaxf(m, x[k]);
#pragma unroll
  for (int o = 32; o; o >>= 1) m = fmaxf(m, __shfl_xor(m, o));
  if (lane == 0) red[wave] = m;
  __syncthreads();
  m = fmaxf(fmaxf(red[0], red[1]), fmaxf(red[2], red[3]));
  float s = 0.f;
#pragma unroll
  for (int k = 0; k < 32; ++k) {
    x[k] = exp2f((x[k] - m) * 1.44269504f);
    s += x[k];
  }
#pragma unroll
  for (int o = 32; o; o >>= 1) s += __shfl_xor(s, o);
  if (lane == 0) red[4 + wave] = s;
  __syncthreads();
  s = (red[4] + red[5]) + (red[6] + red[7]);
  float inv = 1.0f / s;
  _Float16* out = (_Float16*)p;
#pragma unroll
  for (int i = 0; i < 8; ++i) {
    f16x4 v;
#pragma unroll
    for (int j = 0; j < 4; ++j) v[j] = (_Float16)(x[i * 4 + j] * inv);
    *(f16x4*)&out[i * 1024 + tid * 4] = v;
  }
}

extern "C" void kernel_launch(void* const* d_in, const int* in_sizes, int n_in,
                              void* d_out, int out_size, void* d_ws, size_t ws_size,
                              hipStream_t stream) {
  const float* f_x = (const float*)d_in[0];   // [4096,512]
  const float* g_S = (const float*)d_in[1];   // [8192,512]
  const float* W_ih = (const float*)d_in[2];  // [2048,512]
  const float* W_hh = (const float*)d_in[3];  // [2048,1024]
  const float* b_ih = (const float*)d_in[4];  // [2048]
  const float* b_hh = (const float*)d_in[5];  // [2048]
  float* hout = (float*)d_out;                // [4096,512]

  char* w = (char*)d_ws;
  float* P32 = (float*)w;                              // 2048*8192*4 = 67108864 (half-batch)
  _Float16* gbase = (_Float16*)(w + 67108864);         // 4096*2048*2 = 16777216
  _Float16* hbufA = (_Float16*)(w + 83886080);         // 4096*512*2  = 4194304
  _Float16* hbufB = (_Float16*)(w + 88080384);         // 4096*512*2  = 4194304
  _Float16* g_h = (_Float16*)(w + 92274688);           // 8192*512*2  = 8388608
  _Float16* rbuf = (_Float16*)(w + 100663296);         // 4096*512*2  = 4194304
  float* bsum = (float*)(w + 104857600);               // 2048*4      = 8192
  _Float16* gT = (_Float16*)(w + 109051904);           // 512*8192*2  = 8388608
  _Float16* wih_h = (_Float16*)(w + 117440512);        // 2048*512*2  = 2097152
  _Float16* whh_h = (_Float16*)(w + 119537664);        // 2048*1024*2 = 4194304
  float* c = (float*)(w + 123731968);                  // 4096*512*4  = 8388608
  _Float16* h_lo = (_Float16*)(w + 132120576);         // 4096*512*2  = 4194304
  // total 136314880 bytes (unchanged)

  prep_g<<<dim3(S_DIM / 64, D_DIM / 64), 256, 0, stream>>>(g_S, gT, g_h);
  prep_misc<<<5122, 256, 0, stream>>>(W_ih, W_hh, f_x, b_ih, b_hh, wih_h, whh_h,
                                      hbufA, h_lo, c, bsum);

  // gbase = f_x @ W_ih^T  (A = hbufA = f16(f_x), lda 512)
  gemm_bt<128, 128><<<dim3(2048 / 128, 4096 / 128), 256, 0, stream>>>(
      hbufA, 512, wih_h, 512, gbase, 2048, 512);

  for (int it = 0; it < 4; ++it) {
    _Float16* hcur = (it & 1) ? hbufB : hbufA;
    _Float16* hnxt = (it & 1) ? hbufA : hbufB;
    for (int hb = 0; hb < 2; ++hb) {
      const _Float16* hhi = hcur + (size_t)hb * 2048 * 512;
      const _Float16* hlo = h_lo + (size_t)hb * 2048 * 512;
      // scores = h @ g^T : [2048 x 8192] fp32, split-fp16 2-term
      gemm_scores<<<dim3(64, 16), 256, 0, stream>>>(hhi, 512, hlo, g_h, P32);
      softmax_inplace<<<2048, 256, 0, stream>>>(P32);
      // r = P @ g, split-K=8 fp16 partials into dead second halves of P rows
      gemm_rsplit<<<dim3(16, 4, 8), 256, 0, stream>>>((const _Float16*)P32, gT,
                                                      (_Float16*)P32);
      reduce_r<<<1024, 256, 0, stream>>>((const _Float16*)P32,
                                         rbuf + (size_t)hb * 2048 * 512);
    }
    // gates = [h|r] @ W_hh^T + gbase + bsum -> LSTM cell fused in epilogue
    gemm_gates<<<dim3(16, 32), 256, 0, stream>>>(hcur, rbuf, whh_h, gbase, bsum,
                                                 f_x, c, hnxt, h_lo, hout);
  }
  (void)in_sizes; (void)n_in; (void)out_size; (void)ws_size;
}